// Round 8
// baseline (1275.649 us; speedup 1.0000x reference)
//
#include <hip/hip_runtime.h>
#include <math.h>

typedef unsigned long long ull;

#define N      96
#define NN     9216
#define LAT    256
#define ODIM   4656
#define CH     128      // k-chunks for encoder GEMV partials
#define RPC    72       // rows per chunk (128*72 = 9216)
#define ITERS  50
#define CB     12       // mpm blocks
#define CT     768      // threads per mpm block (12 waves)
#define CPB    8        // columns per block

#define SGNMASK2 0x8000000080000000ULL
#define ABSMASK2 0x7FFFFFFF7FFFFFFFULL

// ---- workspace layout (float offsets) ----
#define WS_PART  0                      // [2][CH][LAT] = 65536
#define WS_OUTS  65536                  // 4656 sigmoid outputs
#define WS_KL    70192                  // 1
#define WS_BCE   70193                  // 1 (atomic accumulator)
#define WS_NSLOT 70208                  // [2][12][16] floats = 384 (64B/slot)
#define WS_XBUF  70592                  // [2][9216] floats, row-major x, 8B aligned

__device__ __forceinline__ int tri(int i, int j) {   // i <= j
    return i * N - i * (i - 1) / 2 + (j - i);
}

__device__ __forceinline__ int tri_row(int o) {
    int i = (int)floorf((193.0f - sqrtf((float)(37249 - 8 * o))) * 0.5f);
    i = max(0, min(95, i));
    while ((i + 1) * N - (i + 1) * i / 2 <= o) ++i;
    while (i * N - i * (i - 1) / 2 > o) --i;
    return i;
}

// ---- kA: encoder GEMV partials + control-word init ----
// Stage s lives in x-bank (s&1) with sign-tag ((s>>1)&1).
// Init bank0 = +0 (tag0; first consumed at s=2 expecting tag1),
// bank1 = -0 (tag1; first consumed at s=1 expecting tag0).
__global__ __launch_bounds__(256) void kA_gemv(const float* __restrict__ h,
                                               const float* __restrict__ W1,
                                               const float* __restrict__ W2,
                                               float* __restrict__ ws) {
    __shared__ float hs[RPC];
    int t = threadIdx.x, c = blockIdx.x;
    if (c == 0) {
        if (t < 2) ws[WS_KL + t] = 0.f;                        // KL, BCE
        if (t < CB * 16) {
            ws[WS_NSLOT + t]           = 0.0f;                 // bank0: +0
            ws[WS_NSLOT + CB * 16 + t] = -0.0f;                // bank1: -0
        }
    }
    for (int z = c * 256 + t; z < NN; z += CH * 256) {
        ws[WS_XBUF + z]      = 0.0f;                           // bank0: +0
        ws[WS_XBUF + NN + z] = -0.0f;                          // bank1: -0
    }
    int k0 = c * RPC;
    if (t < RPC) hs[t] = h[k0 + t];
    __syncthreads();
    float a1 = 0.f, a2 = 0.f;
    #pragma unroll 4
    for (int kk = 0; kk < RPC; ++kk) {
        float hv = hs[kk];
        a1 = fmaf(hv, W1[(k0 + kk) * LAT + t], a1);
        a2 = fmaf(hv, W2[(k0 + kk) * LAT + t], a2);
    }
    ws[WS_PART + c * LAT + t]        = a1;
    ws[WS_PART + (CH + c) * LAT + t] = a2;
}

// ---- kB: reduce partials -> z ; KL ; decoder ; sigmoid ; BCE ----
__global__ __launch_bounds__(256) void kB_dec(const float* __restrict__ eps,
                                              const float* __restrict__ be11,
                                              const float* __restrict__ be12,
                                              const float* __restrict__ Wd1,
                                              const float* __restrict__ bd1,
                                              const float* __restrict__ Wd2,
                                              const float* __restrict__ bd2,
                                              const float* __restrict__ adj,
                                              float* __restrict__ ws) {
    __shared__ float zi[LAT];
    __shared__ float hid[LAT];
    __shared__ float red[256];
    int t = threadIdx.x;
    const float* p = ws + WS_PART;
    float mu = 0.f, ls = 0.f;
    #pragma unroll 8
    for (int c = 0; c < CH; ++c) {
        mu += p[c * LAT + t];
        ls += p[(CH + c) * LAT + t];
    }
    mu += be11[t];
    ls += be12[t];
    zi[t] = eps[t] * expf(0.5f * ls) + mu;
    red[t] = 1.0f + ls - mu * mu - expf(ls);
    __syncthreads();
    for (int s = 128; s > 0; s >>= 1) {
        if (t < s) red[t] += red[t + s];
        __syncthreads();
    }
    if (blockIdx.x == 0 && t == 0) ws[WS_KL] = -0.5f * red[0] / 9216.0f;
    __syncthreads();
    float acc = 0.f;
    #pragma unroll 8
    for (int k = 0; k < LAT; ++k) acc = fmaf(zi[k], Wd1[k * LAT + t], acc);
    hid[t] = fmaxf(acc + bd1[t], 0.f);
    __syncthreads();
    int o = blockIdx.x * 256 + t;
    float term = 0.f;
    if (o < ODIM) {
        float a2 = 0.f;
        #pragma unroll 8
        for (int k = 0; k < LAT; ++k) a2 = fmaf(hid[k], Wd2[k * ODIM + o], a2);
        float y = a2 + bd2[o];
        float s = 1.0f / (1.0f + expf(-y));
        ws[WS_OUTS + o] = s;
        int i = tri_row(o);
        int j = i + (o - (i * N - i * (i - 1) / 2));
        float inp = adj[i * N + j];
        float li = fmaxf(logf(inp), -100.0f);
        float l1 = fmaxf(log1pf(-inp), -100.0f);
        term = s * li + (1.0f - s) * l1;
    }
    red[t] = term;
    __syncthreads();
    for (int s = 128; s > 0; s >>= 1) {
        if (t < s) red[t] += red[t + s];
        __syncthreads();
    }
    if (t == 0) atomicAdd(ws + WS_BCE, red[0]);
}

// ---- kC: MPM, 12 blocks x 768 threads, fold-in consumption (no x staging) ----
__global__ __launch_bounds__(CT, 3) void kC_mpm(const float* __restrict__ adj,
                                                float* __restrict__ ws,
                                                float* __restrict__ out) {
    __shared__ __align__(16) float Brow[CPB][N];
    __shared__ __align__(16) float Scol[CPB][N];
    __shared__ __align__(16) float Mv[CPB][N];
    __shared__ __align__(16) float Pout[N][CPB];    // own columns of current x
    __shared__ float ds[N], drs[N], ft[N];
    __shared__ float ftr_sh[CPB];
    __shared__ float wred[CT / 64];
    __shared__ float s_inv;

    int t = threadIdx.x, bid = blockIdx.x;
    int jj = t % N, al = t / N;          // al 0..7
    int a  = bid * CPB + al;             // global column owned by this thread

    const float* outs = ws + WS_OUTS;
    float* xbuf  = ws + WS_XBUF;         // [2][NN] row-major x
    float* nslot = ws + WS_NSLOT;        // [2][CB][16]

    // ---- local build ----
    if (t < N) {
        ds[t]  = adj[t * N + t];
        drs[t] = outs[tri(t, t)];
        const float4* ar = (const float4*)(adj + t * N);
        float s1 = 0.f;
        #pragma unroll
        for (int q = 0; q < N / 4; ++q) {
            float4 v = ar[q];
            s1 += v.x + v.y + v.z + v.w;
        }
        ft[t] = s1;
    }
    __syncthreads();
    {
        int lo = min(a, jj), hi = max(a, jj);
        Mv[al][jj] = outs[tri(lo, hi)];            // rec(a, jj)
    }
    __syncthreads();
    if (t < CPB) {
        float s2 = 0.f;
        for (int b = 0; b < N; ++b) s2 += Mv[t][b];
        ftr_sh[t] = s2;
    }
    __syncthreads();
    Brow[al][jj] = (jj == a) ? 0.f : (Mv[al][jj] * drs[a]) * drs[jj];
    Scol[al][jj] = (ds[jj] * drs[a]) * (1.0f / (fabsf(ft[jj] - ftr_sh[al]) + 1.0f));

    // Aoff row jj (iteration-invariant; compiler may remat from L1 - fine)
    float arow[N];
    {
        const float* arp = adj + jj * N;
        float di = ds[jj];
        #pragma unroll
        for (int j = 0; j < N; ++j)
            arow[j] = (j == jj) ? 0.f : (arp[j] * di) * ds[j];
    }
    __syncthreads();

    // ---- 50 MPM iterations ----
    float acc = 0.f;
    for (int s = 0; s < ITERS; ++s) {
        float m = 0.f;
        float xown;
        if (s == 0) {
            // x0 uniform = 1/96, ||x0|| = 1
            const float v0 = (float)(1.0 / 96.0);
            xown = v0;
            #pragma unroll
            for (int q = 0; q < N / 4; ++q) {
                float4 bw = *(const float4*)&Brow[al][q * 4];
                m = fmaxf(m, fmaxf(fmaxf(bw.x, bw.y), fmaxf(bw.z, bw.w)));
            }
            m *= v0;
            if (t == 0) s_inv = 1.0f;
        } else {
            // own 8 columns from LDS (written by phase C of s-1)
            xown = Pout[jj][al];
            {
                const float* bq = &Brow[al][bid * CPB];
                #pragma unroll
                for (int c = 0; c < CPB; ++c)
                    m = fmaxf(m, bq[c] * Pout[jj][c]);
            }
            // fold other producers' chunks, rotated order, straight from global
            const ull want2 = ((s >> 1) & 1) ? SGNMASK2 : 0ULL;
            const ull* bank = (const ull*)(xbuf + (s & 1) * NN);
            #pragma unroll 1
            for (int qi = 1; qi < CB; ++qi) {
                int q = bid + qi; if (q >= CB) q -= CB;
                const ull* p = bank + jj * 48 + q * 4;
                ull v0, v1, v2, v3;
                for (;;) {
                    v0 = __hip_atomic_load(p + 0, __ATOMIC_RELAXED, __HIP_MEMORY_SCOPE_AGENT);
                    v1 = __hip_atomic_load(p + 1, __ATOMIC_RELAXED, __HIP_MEMORY_SCOPE_AGENT);
                    v2 = __hip_atomic_load(p + 2, __ATOMIC_RELAXED, __HIP_MEMORY_SCOPE_AGENT);
                    v3 = __hip_atomic_load(p + 3, __ATOMIC_RELAXED, __HIP_MEMORY_SCOPE_AGENT);
                    bool okk = ((v0 & SGNMASK2) == want2) & ((v1 & SGNMASK2) == want2) &
                               ((v2 & SGNMASK2) == want2) & ((v3 & SGNMASK2) == want2);
                    if (okk) break;
                    __builtin_amdgcn_s_sleep(1);
                }
                v0 &= ABSMASK2; v1 &= ABSMASK2; v2 &= ABSMASK2; v3 &= ABSMASK2;
                float4 bq0 = *(const float4*)&Brow[al][q * CPB];
                float4 bq1 = *(const float4*)&Brow[al][q * CPB + 4];
                m = fmaxf(m, bq0.x * __uint_as_float((unsigned)v0));
                m = fmaxf(m, bq0.y * __uint_as_float((unsigned)(v0 >> 32)));
                m = fmaxf(m, bq0.z * __uint_as_float((unsigned)v1));
                m = fmaxf(m, bq0.w * __uint_as_float((unsigned)(v1 >> 32)));
                m = fmaxf(m, bq1.x * __uint_as_float((unsigned)v2));
                m = fmaxf(m, bq1.y * __uint_as_float((unsigned)(v2 >> 32)));
                m = fmaxf(m, bq1.z * __uint_as_float((unsigned)v3));
                m = fmaxf(m, bq1.w * __uint_as_float((unsigned)(v3 >> 32)));
            }
        }
        Mv[al][jj] = m;

        // ---- norm poll (wave 0; published alongside x_s -> usually instant) ----
        if (s > 0 && t < 64) {
            const unsigned esn = (unsigned)((s >> 1) & 1);
            float pv = 0.f;
            bool done = (t >= CB);
            const unsigned* np = (const unsigned*)(nslot + (s & 1) * CB * 16);
            while (!__all(done)) {
                if (!done) {
                    unsigned u = __hip_atomic_load(&np[t * 16], __ATOMIC_RELAXED,
                                                   __HIP_MEMORY_SCOPE_AGENT);
                    if ((u >> 31) == esn) { pv = __uint_as_float(u & 0x7FFFFFFFu); done = true; }
                }
                __builtin_amdgcn_s_sleep(1);
            }
            #pragma unroll
            for (int off = 8; off > 0; off >>= 1) pv += __shfl_xor(pv, off, 16);
            if (t == 0) s_inv = 1.0f / sqrtf(pv);
        }
        __syncthreads();                            // sync2 (Mv + s_inv + Pout reads done)

        // ---- phase C: x_new[jj,a] = x[jj][a]*Sd + sum_j arow[j]*M[j,a] ----
        float r = xown * Scol[al][jj];
        #pragma unroll
        for (int q = 0; q < N / 4; ++q) {
            float4 mv = *(const float4*)&Mv[al][q * 4];
            r = fmaf(arow[q * 4 + 0], mv.x, r);
            r = fmaf(arow[q * 4 + 1], mv.y, r);
            r = fmaf(arow[q * 4 + 2], mv.z, r);
            r = fmaf(arow[q * 4 + 3], mv.w, r);
        }
        acc = r * s_inv;
        Pout[jj][al] = acc;

        // block partial of ||x_{s+1}||^2
        float ssq = acc * acc;
        #pragma unroll
        for (int off = 32; off > 0; off >>= 1) ssq += __shfl_xor(ssq, off);
        if ((t & 63) == 0) wred[t >> 6] = ssq;
        __syncthreads();                            // sync3 (Pout + wred ready)

        const unsigned tag1 = (unsigned)(((s + 1) >> 1) & 1);
        // coalesced publish: 384 contiguous packed-ull stores (sign-tagged)
        if (s < ITERS - 1 && t < 384) {
            int jjp = t >> 2, c = t & 3;
            float2 pr = *(const float2*)&Pout[jjp][c * 2];
            ull v = (ull)__float_as_uint(pr.x) | ((ull)__float_as_uint(pr.y) << 32);
            if (tag1) v |= SGNMASK2;               // acc >= 0 -> sign bits were 0
            __hip_atomic_store((ull*)(xbuf + ((s + 1) & 1) * NN) + (jjp * 48 + bid * 4 + c),
                               v, __ATOMIC_RELAXED, __HIP_MEMORY_SCOPE_AGENT);
        }
        if (t == 0) {
            float sum = 0.f;
            #pragma unroll
            for (int w = 0; w < CT / 64; ++w) sum += wred[w];
            unsigned u = __float_as_uint(sum) | (tag1 << 31);
            __hip_atomic_store((unsigned*)(nslot + ((s + 1) & 1) * CB * 16 + bid * 16),
                               u, __ATOMIC_RELAXED, __HIP_MEMORY_SCOPE_AGENT);
        }
    }

    // ---- final normalize (poll ||x_50||^2), write output ----
    if (t < 64) {
        const unsigned esf = (unsigned)((ITERS >> 1) & 1);
        float pv = 0.f;
        bool done = (t >= CB);
        const unsigned* np = (const unsigned*)(nslot + (ITERS & 1) * CB * 16);
        while (!__all(done)) {
            if (!done) {
                unsigned u = __hip_atomic_load(&np[t * 16], __ATOMIC_RELAXED,
                                               __HIP_MEMORY_SCOPE_AGENT);
                if ((u >> 31) == esf) { pv = __uint_as_float(u & 0x7FFFFFFFu); done = true; }
            }
            __builtin_amdgcn_s_sleep(1);
        }
        #pragma unroll
        for (int off = 8; off > 0; off >>= 1) pv += __shfl_xor(pv, off, 16);
        if (t == 0) s_inv = 1.0f / sqrtf(pv);
    }
    __syncthreads();
    out[1 + jj * N + a] = acc * s_inv;
    if (bid == 0 && t == 0)
        out[0] = -(ws[WS_BCE] / 4656.0f) + ws[WS_KL];
}

extern "C" void kernel_launch(void* const* d_in, const int* in_sizes, int n_in,
                              void* d_out, int out_size, void* d_ws, size_t ws_size,
                              hipStream_t stream) {
    const float* inf  = (const float*)d_in[0];
    const float* adj  = (const float*)d_in[1];
    const float* eps  = (const float*)d_in[2];
    const float* We11 = (const float*)d_in[3];
    const float* be11 = (const float*)d_in[4];
    const float* We12 = (const float*)d_in[5];
    const float* be12 = (const float*)d_in[6];
    const float* Wd1  = (const float*)d_in[7];
    const float* bd1  = (const float*)d_in[8];
    const float* Wd2  = (const float*)d_in[9];
    const float* bd2  = (const float*)d_in[10];
    float* ws  = (float*)d_ws;
    float* out = (float*)d_out;

    kA_gemv<<<CH, 256, 0, stream>>>(inf, We11, We12, ws);
    kB_dec <<<19, 256, 0, stream>>>(eps, be11, be12, Wd1, bd1, Wd2, bd2, adj, ws);
    kC_mpm <<<CB, CT, 0, stream>>>(adj, ws, out);
}

// Round 9
// 365.873 us; speedup vs baseline: 3.4866x; 3.4866x over previous
//
#include <hip/hip_runtime.h>
#include <math.h>

typedef unsigned long long ull;

#define N      96
#define NN     9216
#define LAT    256
#define ODIM   4656
#define CH     128      // k-chunks for encoder GEMV partials
#define RPC    72       // rows per chunk (128*72 = 9216)
#define ITERS  50
#define CB     12       // mpm blocks
#define CT     768      // threads per mpm block (12 waves)
#define CPB    8        // columns per block

#define SGNMASK2 0x8000000080000000ULL
#define ABSMASK2 0x7FFFFFFF7FFFFFFFULL

// ---- workspace layout (float offsets) ----
#define WS_PART  0                      // [2][CH][LAT] = 65536
#define WS_OUTS  65536                  // 4656 sigmoid outputs
#define WS_KL    70192                  // 1
#define WS_BCE   70193                  // 1 (atomic accumulator)
#define WS_NSLOT 70208                  // [2][12][16] floats = 384 (64B/slot)
#define WS_XBUF  70592                  // [2][9216] floats, COL-major x, 8B aligned

__device__ __forceinline__ int tri(int i, int j) {   // i <= j
    return i * N - i * (i - 1) / 2 + (j - i);
}

__device__ __forceinline__ int tri_row(int o) {
    int i = (int)floorf((193.0f - sqrtf((float)(37249 - 8 * o))) * 0.5f);
    i = max(0, min(95, i));
    while ((i + 1) * N - (i + 1) * i / 2 <= o) ++i;
    while (i * N - i * (i - 1) / 2 > o) --i;
    return i;
}

// ---- kA: encoder GEMV partials + control-word init ----
// Stage s lives in x/norm bank (s&1) with sign-tag ((s>>1)&1).
// Init bank0=+0 (tag0; first consumed at s=2 expecting tag1 -> invalid),
// bank1=-0 (tag1; first consumed at s=1 expecting tag0 -> invalid).
// Within a bank, consecutive stages carry opposite tags, so stale data is
// always tag-invalid; no refresh stores needed.
__global__ __launch_bounds__(256) void kA_gemv(const float* __restrict__ h,
                                               const float* __restrict__ W1,
                                               const float* __restrict__ W2,
                                               float* __restrict__ ws) {
    __shared__ float hs[RPC];
    int t = threadIdx.x, c = blockIdx.x;
    if (c == 0) {
        if (t < 2) ws[WS_KL + t] = 0.f;                        // KL, BCE
        if (t < CB * 16) {
            ws[WS_NSLOT + t]           = 0.0f;                 // bank0: +0
            ws[WS_NSLOT + CB * 16 + t] = -0.0f;                // bank1: -0
        }
    }
    for (int z = c * 256 + t; z < NN; z += CH * 256) {
        ws[WS_XBUF + z]      = 0.0f;                           // bank0: +0
        ws[WS_XBUF + NN + z] = -0.0f;                          // bank1: -0
    }
    int k0 = c * RPC;
    if (t < RPC) hs[t] = h[k0 + t];
    __syncthreads();
    float a1 = 0.f, a2 = 0.f;
    #pragma unroll 4
    for (int kk = 0; kk < RPC; ++kk) {
        float hv = hs[kk];
        a1 = fmaf(hv, W1[(k0 + kk) * LAT + t], a1);
        a2 = fmaf(hv, W2[(k0 + kk) * LAT + t], a2);
    }
    ws[WS_PART + c * LAT + t]        = a1;
    ws[WS_PART + (CH + c) * LAT + t] = a2;
}

// ---- kB: reduce partials -> z ; KL ; decoder ; sigmoid ; BCE ----
__global__ __launch_bounds__(256) void kB_dec(const float* __restrict__ eps,
                                              const float* __restrict__ be11,
                                              const float* __restrict__ be12,
                                              const float* __restrict__ Wd1,
                                              const float* __restrict__ bd1,
                                              const float* __restrict__ Wd2,
                                              const float* __restrict__ bd2,
                                              const float* __restrict__ adj,
                                              float* __restrict__ ws) {
    __shared__ float zi[LAT];
    __shared__ float hid[LAT];
    __shared__ float red[256];
    int t = threadIdx.x;
    const float* p = ws + WS_PART;
    float mu = 0.f, ls = 0.f;
    #pragma unroll 8
    for (int c = 0; c < CH; ++c) {
        mu += p[c * LAT + t];
        ls += p[(CH + c) * LAT + t];
    }
    mu += be11[t];
    ls += be12[t];
    zi[t] = eps[t] * expf(0.5f * ls) + mu;
    red[t] = 1.0f + ls - mu * mu - expf(ls);
    __syncthreads();
    for (int s = 128; s > 0; s >>= 1) {
        if (t < s) red[t] += red[t + s];
        __syncthreads();
    }
    if (blockIdx.x == 0 && t == 0) ws[WS_KL] = -0.5f * red[0] / 9216.0f;
    __syncthreads();
    float acc = 0.f;
    #pragma unroll 8
    for (int k = 0; k < LAT; ++k) acc = fmaf(zi[k], Wd1[k * LAT + t], acc);
    hid[t] = fmaxf(acc + bd1[t], 0.f);
    __syncthreads();
    int o = blockIdx.x * 256 + t;
    float term = 0.f;
    if (o < ODIM) {
        float a2 = 0.f;
        #pragma unroll 8
        for (int k = 0; k < LAT; ++k) a2 = fmaf(hid[k], Wd2[k * ODIM + o], a2);
        float y = a2 + bd2[o];
        float s = 1.0f / (1.0f + expf(-y));
        ws[WS_OUTS + o] = s;
        int i = tri_row(o);
        int j = i + (o - (i * N - i * (i - 1) / 2));
        float inp = adj[i * N + j];
        float li = fmaxf(logf(inp), -100.0f);
        float l1 = fmaxf(log1pf(-inp), -100.0f);
        term = s * li + (1.0f - s) * l1;
    }
    red[t] = term;
    __syncthreads();
    for (int s = 128; s > 0; s >>= 1) {
        if (t < s) red[t] += red[t + s];
        __syncthreads();
    }
    if (t == 0) atomicAdd(ws + WS_BCE, red[0]);
}

// ---- kC: MPM, 12 blocks x 768 threads, col-major x, sign-tag sync,
//      per-wave immediate publish (round-4 structure, no refresh) ----
__global__ __launch_bounds__(CT, 3) void kC_mpm(const float* __restrict__ adj,
                                                float* __restrict__ ws,
                                                float* __restrict__ out) {
    __shared__ float xnT[N][97];        // xnT[col a][row i], pad 97
    __shared__ float Brow[CPB][N];
    __shared__ float Scol[CPB][N];
    __shared__ float Mv[CPB][N];
    __shared__ float ds[N], drs[N], ft[N];
    __shared__ float ftr_sh[CPB];
    __shared__ float wred[CT / 64];
    __shared__ float s_inv;

    int t = threadIdx.x, bid = blockIdx.x;
    int jj = t % N, al = t / N;          // al 0..7
    int a  = bid * CPB + al;             // global column owned by this thread

    const float* outs = ws + WS_OUTS;
    float* xbuf  = ws + WS_XBUF;         // [2][NN] col-major x
    float* nslot = ws + WS_NSLOT;        // [2][CB][16]

    // ---- local build ----
    if (t < N) {
        ds[t]  = adj[t * N + t];
        drs[t] = outs[tri(t, t)];
        const float4* ar = (const float4*)(adj + t * N);
        float s1 = 0.f;
        #pragma unroll
        for (int q = 0; q < N / 4; ++q) {
            float4 v = ar[q];
            s1 += v.x + v.y + v.z + v.w;
        }
        ft[t] = s1;
    }
    __syncthreads();
    {
        int lo = min(a, jj), hi = max(a, jj);
        Mv[al][jj] = outs[tri(lo, hi)];            // rec(a, jj)
    }
    __syncthreads();
    if (t < CPB) {
        float s2 = 0.f;
        for (int b = 0; b < N; ++b) s2 += Mv[t][b];
        ftr_sh[t] = s2;
    }
    __syncthreads();
    Brow[al][jj] = (jj == a) ? 0.f : (Mv[al][jj] * drs[a]) * drs[jj];
    Scol[al][jj] = (ds[jj] * drs[a]) * (1.0f / (fabsf(ft[jj] - ftr_sh[al]) + 1.0f));

    // Aoff row jj (iteration-invariant; compiler may remat from L1 - fine)
    float arow[N];
    {
        const float* arp = adj + jj * N;
        float di = ds[jj];
        #pragma unroll
        for (int j = 0; j < N; ++j)
            arow[j] = (j == jj) ? 0.f : (arp[j] * di) * ds[j];
    }
    __syncthreads();

    // ---- 50 MPM iterations ----
    float acc = 0.f;
    for (int s = 0; s < ITERS; ++s) {
        // ---- stage x_s into LDS (col-major), sign-tag poll, coalesced ----
        if (s == 0) {
            const float v0 = (float)(1.0 / 96.0);
            for (int f = t; f < NN; f += CT) xnT[f / N][f % N] = v0;
            if (t == 0) s_inv = 1.0f;              // ||x0|| == 1 exactly
        } else {
            const ull want = ((s >> 1) & 1) ? SGNMASK2 : 0ULL;
            const ull* src = (const ull*)(xbuf + (s & 1) * NN);
            ull v[6];
            bool ok = false;
            while (!ok) {
                ok = true;
                #pragma unroll
                for (int k = 0; k < 6; ++k)
                    v[k] = __hip_atomic_load(&src[k * CT + t], __ATOMIC_RELAXED,
                                             __HIP_MEMORY_SCOPE_AGENT);
                #pragma unroll
                for (int k = 0; k < 6; ++k)
                    ok &= ((v[k] & SGNMASK2) == want);
                if (!ok) __builtin_amdgcn_s_sleep(1);
            }
            #pragma unroll
            for (int k = 0; k < 6; ++k) {
                ull w = v[k] & ABSMASK2;
                int e = (k * CT + t) * 2;
                int ac = e / N, i = e % N;         // pairs never cross a column
                xnT[ac][i]     = __uint_as_float((unsigned)w);
                xnT[ac][i + 1] = __uint_as_float((unsigned)(w >> 32));
            }
            // norm poll (wave 0; published alongside x_s -> usually instant)
            if (t < 64) {
                const unsigned esn = (unsigned)((s >> 1) & 1);
                float pv = 0.f;
                bool done = (t >= CB);
                const unsigned* np = (const unsigned*)(nslot + (s & 1) * CB * 16);
                while (!__all(done)) {
                    if (!done) {
                        unsigned u = __hip_atomic_load(&np[t * 16], __ATOMIC_RELAXED,
                                                       __HIP_MEMORY_SCOPE_AGENT);
                        if ((u >> 31) == esn) { pv = __uint_as_float(u & 0x7FFFFFFFu); done = true; }
                    }
                    __builtin_amdgcn_s_sleep(1);
                }
                #pragma unroll
                for (int off = 8; off > 0; off >>= 1) pv += __shfl_xor(pv, off, 16);
                if (t == 0) s_inv = 1.0f / sqrtf(pv);
            }
        }
        __syncthreads();                            // sync1 (xnT + s_inv staged)

        // ---- phase B: M[jj, a] = max_b Brow[al][b] * x[jj][b] ----
        float m = 0.f;
        #pragma unroll
        for (int bq = 0; bq < N / 4; ++bq) {
            m = fmaxf(m, Brow[al][bq * 4 + 0] * xnT[bq * 4 + 0][jj]);
            m = fmaxf(m, Brow[al][bq * 4 + 1] * xnT[bq * 4 + 1][jj]);
            m = fmaxf(m, Brow[al][bq * 4 + 2] * xnT[bq * 4 + 2][jj]);
            m = fmaxf(m, Brow[al][bq * 4 + 3] * xnT[bq * 4 + 3][jj]);
        }
        Mv[al][jj] = m;
        __syncthreads();                            // sync2 (Mv ready)

        // ---- phase C: x_new[jj,a] = x[jj][a]*Sd + sum_j arow[j]*M[j,a] ----
        float r = xnT[a][jj] * Scol[al][jj];
        #pragma unroll
        for (int q = 0; q < N / 4; ++q) {
            float4 mv = *(const float4*)&Mv[al][q * 4];
            r = fmaf(arow[q * 4 + 0], mv.x, r);
            r = fmaf(arow[q * 4 + 1], mv.y, r);
            r = fmaf(arow[q * 4 + 2], mv.z, r);
            r = fmaf(arow[q * 4 + 3], mv.w, r);
        }
        acc = r * s_inv;

        // ---- publish immediately, per-wave, packed pairs, col-major ----
        const unsigned tag1 = (unsigned)(((s + 1) >> 1) & 1);
        float nx = __shfl_down(acc, 1);
        if (s < ITERS - 1 && (t & 1) == 0) {
            ull pv = (ull)__float_as_uint(acc) | ((ull)__float_as_uint(nx) << 32);
            if (tag1) pv |= SGNMASK2;               // acc > 0 -> sign bits were 0
            __hip_atomic_store((ull*)(xbuf + ((s + 1) & 1) * NN) + ((a * N + jj) >> 1),
                               pv, __ATOMIC_RELAXED, __HIP_MEMORY_SCOPE_AGENT);
        }

        // block partial of ||x_{s+1}||^2
        float ssq = acc * acc;
        #pragma unroll
        for (int off = 32; off > 0; off >>= 1) ssq += __shfl_xor(ssq, off);
        if ((t & 63) == 0) wred[t >> 6] = ssq;
        __syncthreads();                            // sync3 (wred; xnT/Mv WAR)
        if (t == 0) {
            float sum = 0.f;
            #pragma unroll
            for (int w = 0; w < CT / 64; ++w) sum += wred[w];
            unsigned u = __float_as_uint(sum) | (tag1 << 31);
            __hip_atomic_store((unsigned*)(nslot + ((s + 1) & 1) * CB * 16 + bid * 16),
                               u, __ATOMIC_RELAXED, __HIP_MEMORY_SCOPE_AGENT);
        }
    }

    // ---- final normalize (poll ||x_50||^2), write output ----
    if (t < 64) {
        const unsigned esf = (unsigned)((ITERS >> 1) & 1);
        float pv = 0.f;
        bool done = (t >= CB);
        const unsigned* np = (const unsigned*)(nslot + (ITERS & 1) * CB * 16);
        while (!__all(done)) {
            if (!done) {
                unsigned u = __hip_atomic_load(&np[t * 16], __ATOMIC_RELAXED,
                                               __HIP_MEMORY_SCOPE_AGENT);
                if ((u >> 31) == esf) { pv = __uint_as_float(u & 0x7FFFFFFFu); done = true; }
            }
            __builtin_amdgcn_s_sleep(1);
        }
        #pragma unroll
        for (int off = 8; off > 0; off >>= 1) pv += __shfl_xor(pv, off, 16);
        if (t == 0) s_inv = 1.0f / sqrtf(pv);
    }
    __syncthreads();
    out[1 + jj * N + a] = acc * s_inv;
    if (bid == 0 && t == 0)
        out[0] = -(ws[WS_BCE] / 4656.0f) + ws[WS_KL];
}

extern "C" void kernel_launch(void* const* d_in, const int* in_sizes, int n_in,
                              void* d_out, int out_size, void* d_ws, size_t ws_size,
                              hipStream_t stream) {
    const float* inf  = (const float*)d_in[0];
    const float* adj  = (const float*)d_in[1];
    const float* eps  = (const float*)d_in[2];
    const float* We11 = (const float*)d_in[3];
    const float* be11 = (const float*)d_in[4];
    const float* We12 = (const float*)d_in[5];
    const float* be12 = (const float*)d_in[6];
    const float* Wd1  = (const float*)d_in[7];
    const float* bd1  = (const float*)d_in[8];
    const float* Wd2  = (const float*)d_in[9];
    const float* bd2  = (const float*)d_in[10];
    float* ws  = (float*)d_ws;
    float* out = (float*)d_out;

    kA_gemv<<<CH, 256, 0, stream>>>(inf, We11, We12, ws);
    kB_dec <<<19, 256, 0, stream>>>(eps, be11, be12, Wd1, bd1, Wd2, bd2, adj, ws);
    kC_mpm <<<CB, CT, 0, stream>>>(adj, ws, out);
}

// Round 10
// 364.173 us; speedup vs baseline: 3.5029x; 1.0047x over previous
//
#include <hip/hip_runtime.h>
#include <math.h>

typedef unsigned long long ull;

#define N      96
#define NN     9216
#define LAT    256
#define ODIM   4656
#define CH     128      // k-chunks for encoder GEMV partials
#define RPC    72       // rows per chunk (128*72 = 9216)
#define ITERS  50
#define CB     12       // mpm blocks
#define CT     768      // threads per mpm block (12 waves)
#define CPB    8        // columns per block

#define SGNMASK2 0x8000000080000000ULL
#define ABSMASK2 0x7FFFFFFF7FFFFFFFULL

// ---- workspace layout (float offsets) ----
#define WS_PART  0                      // [2][CH][LAT] = 65536
#define WS_OUTS  65536                  // 4656 sigmoid outputs
#define WS_KL    70192                  // 1
#define WS_BCE   70193                  // 1 (atomic accumulator)
#define WS_XBUF  70592                  // [2][9216] floats, COL-major x, 8B aligned

__device__ __forceinline__ int tri(int i, int j) {   // i <= j
    return i * N - i * (i - 1) / 2 + (j - i);
}

__device__ __forceinline__ int tri_row(int o) {
    int i = (int)floorf((193.0f - sqrtf((float)(37249 - 8 * o))) * 0.5f);
    i = max(0, min(95, i));
    while ((i + 1) * N - (i + 1) * i / 2 <= o) ++i;
    while (i * N - i * (i - 1) / 2 > o) --i;
    return i;
}

// ---- kA: encoder GEMV partials + control-word init ----
// Stage s lives in x-bank (s&1) with sign-tag ((s>>1)&1); x > 0 so the
// sign bit is free. Init bank0=+0 (tag0; first consumed at s=2 expecting
// tag1 -> invalid), bank1=-0 (tag1; first consumed at s=1 expecting tag0
// -> invalid). Consecutive stages in a bank carry opposite tags, so stale
// data self-invalidates; no refresh stores. Norm is computed locally by
// consumers from the staged words (no norm exchange at all).
__global__ __launch_bounds__(256) void kA_gemv(const float* __restrict__ h,
                                               const float* __restrict__ W1,
                                               const float* __restrict__ W2,
                                               float* __restrict__ ws) {
    __shared__ float hs[RPC];
    int t = threadIdx.x, c = blockIdx.x;
    if (c == 0 && t < 2) ws[WS_KL + t] = 0.f;                  // KL, BCE
    for (int z = c * 256 + t; z < NN; z += CH * 256) {
        ws[WS_XBUF + z]      = 0.0f;                           // bank0: +0
        ws[WS_XBUF + NN + z] = -0.0f;                          // bank1: -0
    }
    int k0 = c * RPC;
    if (t < RPC) hs[t] = h[k0 + t];
    __syncthreads();
    float a1 = 0.f, a2 = 0.f;
    #pragma unroll 4
    for (int kk = 0; kk < RPC; ++kk) {
        float hv = hs[kk];
        a1 = fmaf(hv, W1[(k0 + kk) * LAT + t], a1);
        a2 = fmaf(hv, W2[(k0 + kk) * LAT + t], a2);
    }
    ws[WS_PART + c * LAT + t]        = a1;
    ws[WS_PART + (CH + c) * LAT + t] = a2;
}

// ---- kB: reduce partials -> z ; KL ; decoder ; sigmoid ; BCE ----
__global__ __launch_bounds__(256) void kB_dec(const float* __restrict__ eps,
                                              const float* __restrict__ be11,
                                              const float* __restrict__ be12,
                                              const float* __restrict__ Wd1,
                                              const float* __restrict__ bd1,
                                              const float* __restrict__ Wd2,
                                              const float* __restrict__ bd2,
                                              const float* __restrict__ adj,
                                              float* __restrict__ ws) {
    __shared__ float zi[LAT];
    __shared__ float hid[LAT];
    __shared__ float red[256];
    int t = threadIdx.x;
    const float* p = ws + WS_PART;
    float mu = 0.f, ls = 0.f;
    #pragma unroll 8
    for (int c = 0; c < CH; ++c) {
        mu += p[c * LAT + t];
        ls += p[(CH + c) * LAT + t];
    }
    mu += be11[t];
    ls += be12[t];
    zi[t] = eps[t] * expf(0.5f * ls) + mu;
    red[t] = 1.0f + ls - mu * mu - expf(ls);
    __syncthreads();
    for (int s = 128; s > 0; s >>= 1) {
        if (t < s) red[t] += red[t + s];
        __syncthreads();
    }
    if (blockIdx.x == 0 && t == 0) ws[WS_KL] = -0.5f * red[0] / 9216.0f;
    __syncthreads();
    float acc = 0.f;
    #pragma unroll 8
    for (int k = 0; k < LAT; ++k) acc = fmaf(zi[k], Wd1[k * LAT + t], acc);
    hid[t] = fmaxf(acc + bd1[t], 0.f);
    __syncthreads();
    int o = blockIdx.x * 256 + t;
    float term = 0.f;
    if (o < ODIM) {
        float a2 = 0.f;
        #pragma unroll 8
        for (int k = 0; k < LAT; ++k) a2 = fmaf(hid[k], Wd2[k * ODIM + o], a2);
        float y = a2 + bd2[o];
        float s = 1.0f / (1.0f + expf(-y));
        ws[WS_OUTS + o] = s;
        int i = tri_row(o);
        int j = i + (o - (i * N - i * (i - 1) / 2));
        float inp = adj[i * N + j];
        float li = fmaxf(logf(inp), -100.0f);
        float l1 = fmaxf(log1pf(-inp), -100.0f);
        term = s * li + (1.0f - s) * l1;
    }
    red[t] = term;
    __syncthreads();
    for (int s = 128; s > 0; s >>= 1) {
        if (t < s) red[t] += red[t + s];
        __syncthreads();
    }
    if (t == 0) atomicAdd(ws + WS_BCE, red[0]);
}

// ---- kC: MPM, 12 blocks x 768 threads, col-major x, sign-tag sync,
//      per-wave immediate publish, consumer-local norm ----
__global__ __launch_bounds__(CT, 3) void kC_mpm(const float* __restrict__ adj,
                                                float* __restrict__ ws,
                                                float* __restrict__ out) {
    __shared__ float xnT[N][97];        // xnT[col a][row i], pad 97
    __shared__ float Brow[CPB][N];
    __shared__ float Scol[CPB][N];
    __shared__ float Mv[CPB][N];
    __shared__ float ds[N], drs[N], ft[N];
    __shared__ float ftr_sh[CPB];
    __shared__ float wred[CT / 64];

    int t = threadIdx.x, bid = blockIdx.x;
    int wv = t >> 6;                     // wave index 0..11
    int jj = t % N, al = t / N;          // al 0..7
    int a  = bid * CPB + al;             // global column owned by this thread

    const float* outs = ws + WS_OUTS;
    float* xbuf  = ws + WS_XBUF;         // [2][NN] col-major x

    // ---- local build ----
    if (t < N) {
        ds[t]  = adj[t * N + t];
        drs[t] = outs[tri(t, t)];
        const float4* ar = (const float4*)(adj + t * N);
        float s1 = 0.f;
        #pragma unroll
        for (int q = 0; q < N / 4; ++q) {
            float4 v = ar[q];
            s1 += v.x + v.y + v.z + v.w;
        }
        ft[t] = s1;
    }
    __syncthreads();
    {
        int lo = min(a, jj), hi = max(a, jj);
        Mv[al][jj] = outs[tri(lo, hi)];            // rec(a, jj)
    }
    __syncthreads();
    if (t < CPB) {
        float s2 = 0.f;
        for (int b = 0; b < N; ++b) s2 += Mv[t][b];
        ftr_sh[t] = s2;
    }
    __syncthreads();
    Brow[al][jj] = (jj == a) ? 0.f : (Mv[al][jj] * drs[a]) * drs[jj];
    Scol[al][jj] = (ds[jj] * drs[a]) * (1.0f / (fabsf(ft[jj] - ftr_sh[al]) + 1.0f));

    // Aoff row jj (iteration-invariant; compiler may remat from L1/L2 - fine)
    float arow[N];
    {
        const float* arp = adj + jj * N;
        float di = ds[jj];
        #pragma unroll
        for (int j = 0; j < N; ++j)
            arow[j] = (j == jj) ? 0.f : (arp[j] * di) * ds[j];
    }
    __syncthreads();

    // ---- 50 MPM iterations ----
    float acc = 0.f;
    for (int s = 0; s < ITERS; ++s) {
        // ---- stage x_s into LDS (col-major), sign-tag poll, coalesced;
        //      simultaneously accumulate ||pub_s||^2 locally ----
        if (s == 0) {
            const float v0 = (float)(1.0 / 96.0);
            for (int f = t; f < NN; f += CT) xnT[f / N][f % N] = v0;
        } else {
            const ull want = ((s >> 1) & 1) ? SGNMASK2 : 0ULL;
            const ull* src = (const ull*)(xbuf + (s & 1) * NN);
            ull v[6];
            bool ok = false;
            while (!ok) {
                ok = true;
                #pragma unroll
                for (int k = 0; k < 6; ++k)
                    v[k] = __hip_atomic_load(&src[k * CT + t], __ATOMIC_RELAXED,
                                             __HIP_MEMORY_SCOPE_AGENT);
                #pragma unroll
                for (int k = 0; k < 6; ++k)
                    ok &= ((v[k] & SGNMASK2) == want);
                if (!ok) __builtin_amdgcn_s_sleep(1);
            }
            float tssq = 0.f;
            #pragma unroll
            for (int k = 0; k < 6; ++k) {
                ull w = v[k] & ABSMASK2;
                int e = (k * CT + t) * 2;
                int ac = e / N, i = e % N;         // pairs never cross a column
                float f0 = __uint_as_float((unsigned)w);
                float f1 = __uint_as_float((unsigned)(w >> 32));
                xnT[ac][i]     = f0;
                xnT[ac][i + 1] = f1;
                tssq = fmaf(f0, f0, fmaf(f1, f1, tssq));
            }
            #pragma unroll
            for (int off = 32; off > 0; off >>= 1) tssq += __shfl_xor(tssq, off);
            if ((t & 63) == 0) wred[wv] = tssq;
        }
        __syncthreads();                            // sync1 (xnT + wred staged)

        // ---- phase B: M[jj, a] = max_b Brow[al][b] * x[jj][b] ----
        float m = 0.f;
        #pragma unroll
        for (int bq = 0; bq < N / 4; ++bq) {
            m = fmaxf(m, Brow[al][bq * 4 + 0] * xnT[bq * 4 + 0][jj]);
            m = fmaxf(m, Brow[al][bq * 4 + 1] * xnT[bq * 4 + 1][jj]);
            m = fmaxf(m, Brow[al][bq * 4 + 2] * xnT[bq * 4 + 2][jj]);
            m = fmaxf(m, Brow[al][bq * 4 + 3] * xnT[bq * 4 + 3][jj]);
        }
        Mv[al][jj] = m;
        __syncthreads();                            // sync2 (Mv ready)

        // ---- local norm: s_inv = 1/||pub_s|| from wred (all threads) ----
        float s_inv;
        if (s == 0) {
            s_inv = 1.0f;                           // ||x0|| == 1 exactly
        } else {
            float sum = 0.f;
            #pragma unroll
            for (int w = 0; w < CT / 64; ++w) sum += wred[w];
            s_inv = 1.0f / sqrtf(sum);
        }

        // ---- phase C: x_new[jj,a] = x[jj][a]*Sd + sum_j arow[j]*M[j,a] ----
        float r = xnT[a][jj] * Scol[al][jj];
        #pragma unroll
        for (int q = 0; q < N / 4; ++q) {
            float4 mv = *(const float4*)&Mv[al][q * 4];
            r = fmaf(arow[q * 4 + 0], mv.x, r);
            r = fmaf(arow[q * 4 + 1], mv.y, r);
            r = fmaf(arow[q * 4 + 2], mv.z, r);
            r = fmaf(arow[q * 4 + 3], mv.w, r);
        }
        acc = r * s_inv;

        // ---- publish immediately, per-wave, packed pairs, col-major ----
        // (also for s == ITERS-1: final staging round computes ||x_50||)
        const unsigned tag1 = (unsigned)(((s + 1) >> 1) & 1);
        float nx = __shfl_down(acc, 1);
        if ((t & 1) == 0) {
            ull pv = (ull)__float_as_uint(acc) | ((ull)__float_as_uint(nx) << 32);
            if (tag1) pv |= SGNMASK2;               // acc > 0 -> sign bits were 0
            __hip_atomic_store((ull*)(xbuf + ((s + 1) & 1) * NN) + ((a * N + jj) >> 1),
                               pv, __ATOMIC_RELAXED, __HIP_MEMORY_SCOPE_AGENT);
        }
        __syncthreads();                            // sync3 (xnT/Mv/wred WAR)
    }

    // ---- final: poll stage-50 words, local ||x_50||^2, write output ----
    {
        const ull want = ((ITERS >> 1) & 1) ? SGNMASK2 : 0ULL;
        const ull* src = (const ull*)(xbuf + (ITERS & 1) * NN);
        ull v[6];
        bool ok = false;
        while (!ok) {
            ok = true;
            #pragma unroll
            for (int k = 0; k < 6; ++k)
                v[k] = __hip_atomic_load(&src[k * CT + t], __ATOMIC_RELAXED,
                                         __HIP_MEMORY_SCOPE_AGENT);
            #pragma unroll
            for (int k = 0; k < 6; ++k)
                ok &= ((v[k] & SGNMASK2) == want);
            if (!ok) __builtin_amdgcn_s_sleep(1);
        }
        float tssq = 0.f;
        #pragma unroll
        for (int k = 0; k < 6; ++k) {
            ull w = v[k] & ABSMASK2;
            float f0 = __uint_as_float((unsigned)w);
            float f1 = __uint_as_float((unsigned)(w >> 32));
            tssq = fmaf(f0, f0, fmaf(f1, f1, tssq));
        }
        #pragma unroll
        for (int off = 32; off > 0; off >>= 1) tssq += __shfl_xor(tssq, off);
        if ((t & 63) == 0) wred[wv] = tssq;
        __syncthreads();
        float sum = 0.f;
        #pragma unroll
        for (int w = 0; w < CT / 64; ++w) sum += wred[w];
        float s_invf = 1.0f / sqrtf(sum);
        out[1 + jj * N + a] = acc * s_invf;
        if (bid == 0 && t == 0)
            out[0] = -(ws[WS_BCE] / 4656.0f) + ws[WS_KL];
    }
}

extern "C" void kernel_launch(void* const* d_in, const int* in_sizes, int n_in,
                              void* d_out, int out_size, void* d_ws, size_t ws_size,
                              hipStream_t stream) {
    const float* inf  = (const float*)d_in[0];
    const float* adj  = (const float*)d_in[1];
    const float* eps  = (const float*)d_in[2];
    const float* We11 = (const float*)d_in[3];
    const float* be11 = (const float*)d_in[4];
    const float* We12 = (const float*)d_in[5];
    const float* be12 = (const float*)d_in[6];
    const float* Wd1  = (const float*)d_in[7];
    const float* bd1  = (const float*)d_in[8];
    const float* Wd2  = (const float*)d_in[9];
    const float* bd2  = (const float*)d_in[10];
    float* ws  = (float*)d_ws;
    float* out = (float*)d_out;

    kA_gemv<<<CH, 256, 0, stream>>>(inf, We11, We12, ws);
    kB_dec <<<19, 256, 0, stream>>>(eps, be11, be12, Wd1, bd1, Wd2, bd2, adj, ws);
    kC_mpm <<<CB, CT, 0, stream>>>(adj, ws, out);
}